// Round 19
// baseline (285.860 us; speedup 1.0000x reference)
//
#include <hip/hip_runtime.h>
#include <math.h>

#define BB 4
#define NN 4096
#define MM 4096
#define TI 128
#define TJ 128
#define NTI (NN / TI)   // 32
#define NTJ (MM / TJ)   // 32
#define NROW (BB * NN)  // 16384
#define NCOL (BB * MM)  // 16384

#define L2E100 144.26950408889634f   // 100*log2(e); exp(-100 d) = exp2(-L2E100 d)
#define SCLAMP 126.0f                // max safe exp2 arg for the shift factor

typedef __attribute__((ext_vector_type(2))) float f32x2;

// ---------- cross-lane helpers ----------
__device__ __forceinline__ float dpp_sum16(float v) {
    float t;
    t = __int_as_float(__builtin_amdgcn_update_dpp(0, __float_as_int(v), 0x111, 0xF, 0xF, true)); v += t;
    t = __int_as_float(__builtin_amdgcn_update_dpp(0, __float_as_int(v), 0x112, 0xF, 0xF, true)); v += t;
    t = __int_as_float(__builtin_amdgcn_update_dpp(0, __float_as_int(v), 0x114, 0xF, 0xF, true)); v += t;
    t = __int_as_float(__builtin_amdgcn_update_dpp(0, __float_as_int(v), 0x118, 0xF, 0xF, true)); v += t;
    return v;  // total in lane (tx==15)
}
__device__ __forceinline__ float dpp_min16(float v) {
    float t;
    t = __int_as_float(__builtin_amdgcn_update_dpp(__float_as_int(v), __float_as_int(v), 0x111, 0xF, 0xF, false)); v = fminf(v, t);
    t = __int_as_float(__builtin_amdgcn_update_dpp(__float_as_int(v), __float_as_int(v), 0x112, 0xF, 0xF, false)); v = fminf(v, t);
    t = __int_as_float(__builtin_amdgcn_update_dpp(__float_as_int(v), __float_as_int(v), 0x114, 0xF, 0xF, false)); v = fminf(v, t);
    t = __int_as_float(__builtin_amdgcn_update_dpp(__float_as_int(v), __float_as_int(v), 0x118, 0xF, 0xF, false)); v = fminf(v, t);
    return v;  // min in lane (tx==15)
}
__device__ __forceinline__ float bperm(float v, int addr) {
    return __int_as_float(__builtin_amdgcn_ds_bpermute(addr, __float_as_int(v)));
}

// ---------- packed helpers ----------
__device__ __forceinline__ f32x2 vmin2(f32x2 a, f32x2 b) {
    f32x2 r; r.x = fminf(a.x, b.x); r.y = fminf(a.y, b.y); return r;
}
__device__ __forceinline__ f32x2 vmax0(f32x2 a) {
    f32x2 r; r.x = fmaxf(a.x, 0.0f); r.y = fmaxf(a.y, 0.0f); return r;
}
__device__ __forceinline__ f32x2 vsqrt2(f32x2 a) {
    f32x2 r; r.x = __builtin_amdgcn_sqrtf(a.x); r.y = __builtin_amdgcn_sqrtf(a.y); return r;
}
__device__ __forceinline__ f32x2 vexp2(f32x2 a) {
    f32x2 r; r.x = __builtin_amdgcn_exp2f(a.x); r.y = __builtin_amdgcn_exp2f(a.y); return r;
}
__device__ __forceinline__ f32x2 pair_d2_pk(f32x2 Xx2, f32x2 Xy2, f32x2 Xz2, f32x2 Xw2,
                                            f32x2 Yx2, f32x2 Yy2, f32x2 Yz2, f32x2 Yw2) {
    f32x2 pq = Xw2 + Yw2;
    pq = Xz2 * Yz2 + pq;
    pq = Xy2 * Yy2 + pq;
    pq = Xx2 * Yx2 + pq;
    return pq;
}

// ---------- staging: X=(-2x,|x|^2), Y=(y,|y|^2); d2 = X.Y + (Xw+Yw) ----------
__device__ __forceinline__ float4 stage_x(const float* p) {
    float a = p[0], b = p[1], c = p[2];
    float4 r; r.x = -2.0f * a; r.y = -2.0f * b; r.z = -2.0f * c;
    r.w = fmaf(a, a, fmaf(b, b, c * c));
    return r;
}
__device__ __forceinline__ float4 stage_y(const float* p) {
    float a = p[0], b = p[1], c = p[2];
    float4 r; r.x = a; r.y = b; r.z = c;
    r.w = fmaf(a, a, fmaf(b, b, c * c));
    return r;
}

// ================= MERGED PATH (needs ~12.6MB ws) =================
// R18's exp factoring (2 trans/pair) cut busy cycles 86K->67K/SIMD as
// predicted, but VGPR 64->88 dropped occupancy 35->19% and cost the win.
// launch_bounds(256,8) pins the register budget to 64 (R15 proved this
// working set fits) to recover the occupancy at the reduced content.

__global__ __launch_bounds__(256, 8)
void merged_pass(const float* __restrict__ x, const float* __restrict__ y,
                 float* __restrict__ sR, float* __restrict__ numR, float* __restrict__ denR,
                 float* __restrict__ sC, float* __restrict__ numC, float* __restrict__ denC) {
    const int bid = blockIdx.x;
    const int b   = bid / (NTI * NTJ);
    const int rem = bid % (NTI * NTJ);
    const int ib  = rem / NTJ, jb = rem % NTJ;
    const int i0  = ib * TI, j0 = jb * TJ;

    __shared__ float4 xs4[TI];
    __shared__ float4 ys4[TJ];
    __shared__ float  arE[TI], acE[TJ], rowmin_s[TI];
    __shared__ float  cm_w[4][TJ];
    __shared__ float  sn_w[4][TJ], sd_w[4][TJ];

    const int t = threadIdx.x;
    if (t < TI) xs4[t] = stage_x(&x[(size_t)(b * NN + i0 + t) * 3]);
    else        ys4[t - TI] = stage_y(&y[(size_t)(b * MM + j0 + (t - TI)) * 3]);
    __syncthreads();

    const int tx = t & 15, ty = t >> 4;
    const int lane = t & 63, wv = t >> 6;
    const int a16 = (lane ^ 16) << 2, a32 = (lane ^ 32) << 2;

    // packed Y fragments: pair p holds cols (2p, 2p+1)
    f32x2 Yx2[4], Yy2[4], Yz2[4], Yw2[4], cm2[4];
#pragma unroll
    for (int p = 0; p < 4; ++p) {
        float4 a = ys4[tx + (2 * p) * 16];
        float4 c = ys4[tx + (2 * p + 1) * 16];
        Yx2[p] = (f32x2){a.x, c.x}; Yy2[p] = (f32x2){a.y, c.y};
        Yz2[p] = (f32x2){a.z, c.z}; Yw2[p] = (f32x2){a.w, c.w};
        cm2[p] = (f32x2){1e30f, 1e30f};
    }

    // ---- micro-pass A: block-local row/col mins (packed, no trans) ----
#pragma unroll
    for (int k = 0; k < 8; ++k) {
        float4 Xv = xs4[ty + k * 16];
        f32x2 Xx2 = (f32x2){Xv.x, Xv.x}, Xy2 = (f32x2){Xv.y, Xv.y};
        f32x2 Xz2 = (f32x2){Xv.z, Xv.z}, Xw2 = (f32x2){Xv.w, Xv.w};
        f32x2 rm2 = (f32x2){1e30f, 1e30f};
#pragma unroll
        for (int p = 0; p < 4; ++p) {
            f32x2 pq = pair_d2_pk(Xx2, Xy2, Xz2, Xw2, Yx2[p], Yy2[p], Yz2[p], Yw2[p]);
            rm2 = vmin2(rm2, pq);
            cm2[p] = vmin2(cm2[p], pq);
        }
        float rmin = dpp_min16(fminf(rm2.x, rm2.y));
        if (tx == 15) rowmin_s[ty + k * 16] = rmin;   // row owned by one wave
    }
#pragma unroll
    for (int p = 0; p < 4; ++p) {
#pragma unroll
        for (int h = 0; h < 2; ++h) {
            float v = h ? cm2[p].y : cm2[p].x;
            v = fminf(v, bperm(v, a16));
            v = fminf(v, bperm(v, a32));
            if (lane < 16) cm_w[wv][lane + (2 * p + h) * 16] = v;
        }
    }
    __syncthreads();

    // ---- local shifts: write unclamped s partial; stash exp2(clamped) ----
    if (t < TI) {
        float s = L2E100 * __builtin_amdgcn_sqrtf(fmaxf(rowmin_s[t], 0.0f));
        arE[t] = __builtin_amdgcn_exp2f(fminf(s, SCLAMP));
        sR[(size_t)jb * NROW + b * NN + i0 + t] = s;
    } else {
        int j = t - TI;
        float m = fminf(fminf(cm_w[0][j], cm_w[1][j]), fminf(cm_w[2][j], cm_w[3][j]));
        float s = L2E100 * __builtin_amdgcn_sqrtf(fmaxf(m, 0.0f));
        acE[j] = __builtin_amdgcn_exp2f(fminf(s, SCLAMP));
        sC[(size_t)ib * NCOL + b * MM + j0 + j] = s;
    }
    __syncthreads();

    // ---- micro-pass B: 2 trans/pair (sqrt + shared exp), factored shifts ----
    const f32x2 nL2 = (f32x2){-L2E100, -L2E100};
    f32x2 acE2[4], nc2[4], dc2[4];
#pragma unroll
    for (int p = 0; p < 4; ++p) {
        acE2[p] = (f32x2){acE[tx + (2 * p) * 16], acE[tx + (2 * p + 1) * 16]};
        nc2[p] = (f32x2){0.0f, 0.0f}; dc2[p] = (f32x2){0.0f, 0.0f};
    }

#pragma unroll
    for (int k = 0; k < 8; ++k) {
        float4 Xv = xs4[ty + k * 16];
        f32x2 Xx2 = (f32x2){Xv.x, Xv.x}, Xy2 = (f32x2){Xv.y, Xv.y};
        f32x2 Xz2 = (f32x2){Xv.z, Xv.z}, Xw2 = (f32x2){Xv.w, Xv.w};
        float arEk = arE[ty + k * 16];
        f32x2 arE2 = (f32x2){arEk, arEk};
        f32x2 nr2 = (f32x2){0.0f, 0.0f}, dr2 = (f32x2){0.0f, 0.0f};
#pragma unroll
        for (int p = 0; p < 4; ++p) {
            f32x2 pq = pair_d2_pk(Xx2, Xy2, Xz2, Xw2, Yx2[p], Yy2[p], Yz2[p], Yw2[p]);
            f32x2 d  = vsqrt2(vmax0(pq));
            f32x2 g  = vexp2(d * nL2);          // exp2(-L*d); may flush to 0
            f32x2 eR = g * arE2;                // = exp2(-L*d + sr_c)
            nr2 = d * eR + nr2;
            dr2 = dr2 + eR;
            f32x2 eC = g * acE2[p];             // = exp2(-L*d + sc_c)
            nc2[p] = d * eC + nc2[p];
            dc2[p] = dc2[p] + eC;
        }
        float vn = dpp_sum16(nr2.x + nr2.y);
        float vd = dpp_sum16(dr2.x + dr2.y);
        if (tx == 15) {
            size_t idx = (size_t)jb * NROW + b * NN + i0 + ty + k * 16;
            numR[idx] = vn;            // one writer per (row, jb)
            denR[idx] = vd;
        }
    }

#pragma unroll
    for (int p = 0; p < 4; ++p) {
#pragma unroll
        for (int h = 0; h < 2; ++h) {
            float vn = h ? nc2[p].y : nc2[p].x;
            float vd = h ? dc2[p].y : dc2[p].x;
            vn += bperm(vn, a16); vd += bperm(vd, a16);
            vn += bperm(vn, a32); vd += bperm(vd, a32);
            if (lane < 16) {
                sn_w[wv][lane + (2 * p + h) * 16] = vn;
                sd_w[wv][lane + (2 * p + h) * 16] = vd;
            }
        }
    }
    __syncthreads();
    if (t < TJ) {
        size_t idx = (size_t)ib * NCOL + b * MM + j0 + t;
        numC[idx] = (sn_w[0][t] + sn_w[1][t]) + (sn_w[2][t] + sn_w[3][t]);
        denC[idx] = (sd_w[0][t] + sd_w[1][t]) + (sd_w[2][t] + sd_w[3][t]);
    }
}

__global__ __launch_bounds__(256)
void finalize2(const float* __restrict__ sR, const float* __restrict__ numR, const float* __restrict__ denR,
               const float* __restrict__ sC, const float* __restrict__ numC, const float* __restrict__ denC,
               float* __restrict__ bsum) {
    const int gid = blockIdx.x * 256 + threadIdx.x;   // 0..32767
    const float* S; const float* NU; const float* DE; int idx;
    if (gid < NROW) { S = sR; NU = numR; DE = denR; idx = gid; }
    else            { S = sC; NU = numC; DE = denC; idx = gid - NROW; }

    float m = 1e30f;
#pragma unroll 4
    for (int pb = 0; pb < 32; ++pb) m = fminf(m, S[(size_t)pb * NROW + idx]);
    const float mc = fminf(m, SCLAMP);     // rebase in CLAMPED shift space
    float nu = 0.0f, de = 0.0f;
#pragma unroll 4
    for (int pb = 0; pb < 32; ++pb) {
        size_t o = (size_t)pb * NROW + idx;
        float f = __builtin_amdgcn_exp2f(mc - fminf(S[o], SCLAMP));   // <= 0 arg
        nu = fmaf(NU[o], f, nu);
        de = fmaf(DE[o], f, de);
    }
    // de==0 only if every weight underflowed -> softmin -> d_min = m/L exactly.
    float q = (de > 1e-35f) ? nu * __builtin_amdgcn_rcpf(de)
                            : m * (1.0f / L2E100);

#pragma unroll
    for (int s = 1; s < 64; s <<= 1) q += __shfl_xor(q, s);
    __shared__ float wsum[4];
    const int t = threadIdx.x;
    if ((t & 63) == 0) wsum[t >> 6] = q;
    __syncthreads();
    if (t == 0) bsum[blockIdx.x] = (wsum[0] + wsum[1]) + (wsum[2] + wsum[3]);
}

__global__ __launch_bounds__(256)
void final_sum(const float* __restrict__ bsum, float* __restrict__ out) {
    const int t = threadIdx.x;
    float s = (t < 128) ? bsum[t] : 0.0f;
#pragma unroll
    for (int m = 1; m < 64; m <<= 1) s += __shfl_xor(s, m);
    __shared__ float wsum[4];
    if ((t & 63) == 0) wsum[t >> 6] = s;
    __syncthreads();
    if (t == 0) out[0] = (wsum[0] + wsum[1] + wsum[2] + wsum[3]) * (1.0f / (float)(BB * NN));
}

// ================= FALLBACK PATH (R15-style, 384KB ws) =================
__global__ __launch_bounds__(256)
void init_ws_kernel(float* ws, float* out) {
    int idx = blockIdx.x * 256 + threadIdx.x;
    if (idx < 2 * 16384) ws[idx] = 1e30f;
    else if (idx < 6 * 16384) ws[idx] = 0.0f;
    if (idx == 0) out[0] = 0.0f;
}

__global__ __launch_bounds__(256)
void pass1_min(const float* __restrict__ x, const float* __restrict__ y,
               unsigned int* __restrict__ m2_row, unsigned int* __restrict__ m2_col) {
    const int bid = blockIdx.x;
    const int b   = bid / (NTI * NTJ);
    const int rem = bid % (NTI * NTJ);
    const int i0  = (rem / NTJ) * TI;
    const int j0  = (rem % NTJ) * TJ;

    __shared__ float4 xs4[TI];
    __shared__ float4 ys4[TJ];
    __shared__ float  cm_w[4][TJ];

    const int t = threadIdx.x;
    if (t < TI) xs4[t] = stage_x(&x[(size_t)(b * NN + i0 + t) * 3]);
    else        ys4[t - TI] = stage_y(&y[(size_t)(b * MM + j0 + (t - TI)) * 3]);
    __syncthreads();

    const int tx = t & 15, ty = t >> 4;
    const int lane = t & 63, wv = t >> 6;
    const int a16 = (lane ^ 16) << 2, a32 = (lane ^ 32) << 2;

    f32x2 Yx2[4], Yy2[4], Yz2[4], Yw2[4], cm2[4];
#pragma unroll
    for (int p = 0; p < 4; ++p) {
        float4 a = ys4[tx + (2 * p) * 16];
        float4 c = ys4[tx + (2 * p + 1) * 16];
        Yx2[p] = (f32x2){a.x, c.x}; Yy2[p] = (f32x2){a.y, c.y};
        Yz2[p] = (f32x2){a.z, c.z}; Yw2[p] = (f32x2){a.w, c.w};
        cm2[p] = (f32x2){1e30f, 1e30f};
    }
#pragma unroll
    for (int k = 0; k < 8; ++k) {
        float4 Xv = xs4[ty + k * 16];
        f32x2 Xx2 = (f32x2){Xv.x, Xv.x}, Xy2 = (f32x2){Xv.y, Xv.y};
        f32x2 Xz2 = (f32x2){Xv.z, Xv.z}, Xw2 = (f32x2){Xv.w, Xv.w};
        f32x2 rm2 = (f32x2){1e30f, 1e30f};
#pragma unroll
        for (int p = 0; p < 4; ++p) {
            f32x2 pq = pair_d2_pk(Xx2, Xy2, Xz2, Xw2, Yx2[p], Yy2[p], Yz2[p], Yw2[p]);
            rm2 = vmin2(rm2, pq);
            cm2[p] = vmin2(cm2[p], pq);
        }
        float rmin = dpp_min16(fminf(rm2.x, rm2.y));
        if (tx == 15) atomicMin(&m2_row[b * NN + i0 + ty + k * 16], __float_as_uint(rmin));
    }
#pragma unroll
    for (int p = 0; p < 4; ++p) {
#pragma unroll
        for (int h = 0; h < 2; ++h) {
            float v = h ? cm2[p].y : cm2[p].x;
            v = fminf(v, bperm(v, a16));
            v = fminf(v, bperm(v, a32));
            if (lane < 16) cm_w[wv][lane + (2 * p + h) * 16] = v;
        }
    }
    __syncthreads();
    if (t < TJ) {
        float m = fminf(fminf(cm_w[0][t], cm_w[1][t]), fminf(cm_w[2][t], cm_w[3][t]));
        atomicMin(&m2_col[b * MM + j0 + t], __float_as_uint(m));
    }
}

__global__ __launch_bounds__(256)
void pass2_acc(const float* __restrict__ x, const float* __restrict__ y,
               const unsigned int* __restrict__ m2_row, const unsigned int* __restrict__ m2_col,
               float* __restrict__ num_r, float* __restrict__ den_r,
               float* __restrict__ num_c, float* __restrict__ den_c) {
    const int bid = blockIdx.x;
    const int b   = bid / (NTI * NTJ);
    const int rem = bid % (NTI * NTJ);
    const int i0  = (rem / NTJ) * TI;
    const int j0  = (rem % NTJ) * TJ;

    __shared__ float4 xs4[TI];
    __shared__ float4 ys4[TJ];
    __shared__ float  ar[TI];
    __shared__ float  ac[TJ];
    __shared__ float  sn_w[4][TJ];
    __shared__ float  sd_w[4][TJ];

    const int t = threadIdx.x;
    if (t < TI) {
        xs4[t] = stage_x(&x[(size_t)(b * NN + i0 + t) * 3]);
        ar[t]  = L2E100 * __builtin_amdgcn_sqrtf(fmaxf(__uint_as_float(m2_row[b * NN + i0 + t]), 0.0f));
    } else {
        int j = t - TI;
        ys4[j] = stage_y(&y[(size_t)(b * MM + j0 + j) * 3]);
        ac[j]  = L2E100 * __builtin_amdgcn_sqrtf(fmaxf(__uint_as_float(m2_col[b * MM + j0 + j]), 0.0f));
    }
    __syncthreads();

    const int tx = t & 15, ty = t >> 4;
    const int lane = t & 63, wv = t >> 6;
    const int a16 = (lane ^ 16) << 2, a32 = (lane ^ 32) << 2;
    const f32x2 nL2 = (f32x2){-L2E100, -L2E100};

    f32x2 Yx2[4], Yy2[4], Yz2[4], Yw2[4], sc2[4], nc2[4], dc2[4];
#pragma unroll
    for (int p = 0; p < 4; ++p) {
        float4 a = ys4[tx + (2 * p) * 16];
        float4 c = ys4[tx + (2 * p + 1) * 16];
        Yx2[p] = (f32x2){a.x, c.x}; Yy2[p] = (f32x2){a.y, c.y};
        Yz2[p] = (f32x2){a.z, c.z}; Yw2[p] = (f32x2){a.w, c.w};
        sc2[p] = (f32x2){ac[tx + (2 * p) * 16], ac[tx + (2 * p + 1) * 16]};
        nc2[p] = (f32x2){0.0f, 0.0f}; dc2[p] = (f32x2){0.0f, 0.0f};
    }
#pragma unroll
    for (int k = 0; k < 8; ++k) {
        float4 Xv = xs4[ty + k * 16];
        f32x2 Xx2 = (f32x2){Xv.x, Xv.x}, Xy2 = (f32x2){Xv.y, Xv.y};
        f32x2 Xz2 = (f32x2){Xv.z, Xv.z}, Xw2 = (f32x2){Xv.w, Xv.w};
        float srk = ar[ty + k * 16];
        f32x2 sr2 = (f32x2){srk, srk};
        f32x2 nr2 = (f32x2){0.0f, 0.0f}, dr2 = (f32x2){0.0f, 0.0f};
#pragma unroll
        for (int p = 0; p < 4; ++p) {
            f32x2 pq = pair_d2_pk(Xx2, Xy2, Xz2, Xw2, Yx2[p], Yy2[p], Yz2[p], Yw2[p]);
            f32x2 d  = vsqrt2(vmax0(pq));
            f32x2 eR = vexp2(d * nL2 + sr2);
            nr2 = d * eR + nr2;
            dr2 = dr2 + eR;
            f32x2 eC = vexp2(d * nL2 + sc2[p]);
            nc2[p] = d * eC + nc2[p];
            dc2[p] = dc2[p] + eC;
        }
        float vn = dpp_sum16(nr2.x + nr2.y);
        float vd = dpp_sum16(dr2.x + dr2.y);
        if (tx == 15) {
            atomicAdd(&num_r[b * NN + i0 + ty + k * 16], vn);
            atomicAdd(&den_r[b * NN + i0 + ty + k * 16], vd);
        }
    }
#pragma unroll
    for (int p = 0; p < 4; ++p) {
#pragma unroll
        for (int h = 0; h < 2; ++h) {
            float vn = h ? nc2[p].y : nc2[p].x;
            float vd = h ? dc2[p].y : dc2[p].x;
            vn += bperm(vn, a16); vd += bperm(vd, a16);
            vn += bperm(vn, a32); vd += bperm(vd, a32);
            if (lane < 16) {
                sn_w[wv][lane + (2 * p + h) * 16] = vn;
                sd_w[wv][lane + (2 * p + h) * 16] = vd;
            }
        }
    }
    __syncthreads();
    if (t < TJ) {
        atomicAdd(&num_c[b * MM + j0 + t], (sn_w[0][t] + sn_w[1][t]) + (sn_w[2][t] + sn_w[3][t]));
        atomicAdd(&den_c[b * MM + j0 + t], (sd_w[0][t] + sd_w[1][t]) + (sd_w[2][t] + sd_w[3][t]));
    }
}

__global__ __launch_bounds__(256)
void finalize_kernel(const float* __restrict__ num_r, const float* __restrict__ den_r,
                     const float* __restrict__ num_c, const float* __restrict__ den_c,
                     float* __restrict__ out) {
    const int gid = blockIdx.x * 256 + threadIdx.x;
    float s = 0.0f;
    for (int idx = gid; idx < BB * NN; idx += 32 * 256) {
        s = fmaf(num_r[idx], __builtin_amdgcn_rcpf(den_r[idx]), s);
        s = fmaf(num_c[idx], __builtin_amdgcn_rcpf(den_c[idx]), s);
    }
#pragma unroll
    for (int m = 1; m < 64; m <<= 1) s += __shfl_xor(s, m);
    __shared__ float wsum[4];
    const int t = threadIdx.x;
    if ((t & 63) == 0) wsum[t >> 6] = s;
    __syncthreads();
    if (t == 0) {
        float v = (wsum[0] + wsum[1] + wsum[2] + wsum[3]) * (1.0f / (float)(BB * NN));
        atomicAdd(out, v);
    }
}

extern "C" void kernel_launch(void* const* d_in, const int* in_sizes, int n_in,
                              void* d_out, int out_size, void* d_ws, size_t ws_size,
                              hipStream_t stream) {
    const float* x = (const float*)d_in[0];
    const float* y = (const float*)d_in[1];
    float* ws = (float*)d_ws;

    const size_t PART = (size_t)32 * NROW;      // 524288 floats per partial array
    const size_t need = (6 * PART + 256) * sizeof(float);  // ~12.6MB

    if (ws_size >= need) {
        float* sR   = ws;
        float* numR = ws + PART;
        float* denR = ws + 2 * PART;
        float* sC   = ws + 3 * PART;
        float* numC = ws + 4 * PART;
        float* denC = ws + 5 * PART;
        float* bsum = ws + 6 * PART;

        hipLaunchKernelGGL(merged_pass, dim3(BB * NTI * NTJ), dim3(256), 0, stream,
                           x, y, sR, numR, denR, sC, numC, denC);
        hipLaunchKernelGGL(finalize2, dim3(128), dim3(256), 0, stream,
                           sR, numR, denR, sC, numC, denC, bsum);
        hipLaunchKernelGGL(final_sum, dim3(1), dim3(256), 0, stream, bsum, (float*)d_out);
    } else {
        unsigned int* m2_row = (unsigned int*)(ws);
        unsigned int* m2_col = (unsigned int*)(ws + 16384);
        float* num_r = ws + 32768;
        float* den_r = ws + 49152;
        float* num_c = ws + 65536;
        float* den_c = ws + 81920;

        hipLaunchKernelGGL(init_ws_kernel, dim3(384), dim3(256), 0, stream, ws, (float*)d_out);
        dim3 grid(BB * NTI * NTJ);
        hipLaunchKernelGGL(pass1_min, grid, dim3(256), 0, stream, x, y, m2_row, m2_col);
        hipLaunchKernelGGL(pass2_acc, grid, dim3(256), 0, stream,
                           x, y, m2_row, m2_col, num_r, den_r, num_c, den_c);
        hipLaunchKernelGGL(finalize_kernel, dim3(32), dim3(256), 0, stream,
                           num_r, den_r, num_c, den_c, (float*)d_out);
    }
}

// Round 20
// 63.312 us; speedup vs baseline: 4.5151x; 4.5151x over previous
//
#include <hip/hip_runtime.h>
#include <math.h>

#define BB 4
#define NN 4096
#define MM 4096
#define TI 128
#define TJ 128
#define NTI (NN / TI)   // 32
#define NTJ (MM / TJ)   // 32
#define NROW (BB * NN)  // 16384
#define NCOL (BB * MM)  // 16384

#define L2E100 144.26950408889634f   // 100*log2(e); exp(-100 d) = exp2(-L2E100 d)

typedef __attribute__((ext_vector_type(2))) float f32x2;

// ---------- cross-lane helpers ----------
__device__ __forceinline__ float dpp_sum16(float v) {
    float t;
    t = __int_as_float(__builtin_amdgcn_update_dpp(0, __float_as_int(v), 0x111, 0xF, 0xF, true)); v += t;
    t = __int_as_float(__builtin_amdgcn_update_dpp(0, __float_as_int(v), 0x112, 0xF, 0xF, true)); v += t;
    t = __int_as_float(__builtin_amdgcn_update_dpp(0, __float_as_int(v), 0x114, 0xF, 0xF, true)); v += t;
    t = __int_as_float(__builtin_amdgcn_update_dpp(0, __float_as_int(v), 0x118, 0xF, 0xF, true)); v += t;
    return v;  // total in lane (tx==15)
}
__device__ __forceinline__ float dpp_min16(float v) {
    float t;
    t = __int_as_float(__builtin_amdgcn_update_dpp(__float_as_int(v), __float_as_int(v), 0x111, 0xF, 0xF, false)); v = fminf(v, t);
    t = __int_as_float(__builtin_amdgcn_update_dpp(__float_as_int(v), __float_as_int(v), 0x112, 0xF, 0xF, false)); v = fminf(v, t);
    t = __int_as_float(__builtin_amdgcn_update_dpp(__float_as_int(v), __float_as_int(v), 0x114, 0xF, 0xF, false)); v = fminf(v, t);
    t = __int_as_float(__builtin_amdgcn_update_dpp(__float_as_int(v), __float_as_int(v), 0x118, 0xF, 0xF, false)); v = fminf(v, t);
    return v;  // min in lane (tx==15)
}
__device__ __forceinline__ float bperm(float v, int addr) {
    return __int_as_float(__builtin_amdgcn_ds_bpermute(addr, __float_as_int(v)));
}

// ---------- packed helpers ----------
__device__ __forceinline__ f32x2 vmin2(f32x2 a, f32x2 b) {
    f32x2 r; r.x = fminf(a.x, b.x); r.y = fminf(a.y, b.y); return r;
}
__device__ __forceinline__ f32x2 vmax0(f32x2 a) {
    f32x2 r; r.x = fmaxf(a.x, 0.0f); r.y = fmaxf(a.y, 0.0f); return r;
}
__device__ __forceinline__ f32x2 vsqrt2(f32x2 a) {
    f32x2 r; r.x = __builtin_amdgcn_sqrtf(a.x); r.y = __builtin_amdgcn_sqrtf(a.y); return r;
}
__device__ __forceinline__ f32x2 vexp2(f32x2 a) {
    f32x2 r; r.x = __builtin_amdgcn_exp2f(a.x); r.y = __builtin_amdgcn_exp2f(a.y); return r;
}
// SHARED packed d2: used by BOTH micro-passes -> bitwise-identical d2, so the
// block-local shift satisfies sr <= L*d exactly (exp2 arg <= 0, no overflow).
__device__ __forceinline__ f32x2 pair_d2_pk(f32x2 Xx2, f32x2 Xy2, f32x2 Xz2, f32x2 Xw2,
                                            f32x2 Yx2, f32x2 Yy2, f32x2 Yz2, f32x2 Yw2) {
    f32x2 pq = Xw2 + Yw2;
    pq = Xz2 * Yz2 + pq;
    pq = Xy2 * Yy2 + pq;
    pq = Xx2 * Yx2 + pq;
    return pq;
}

// ---------- staging: X=(-2x,|x|^2), Y=(y,|y|^2); d2 = X.Y + (Xw+Yw) ----------
__device__ __forceinline__ float4 stage_x(const float* p) {
    float a = p[0], b = p[1], c = p[2];
    float4 r; r.x = -2.0f * a; r.y = -2.0f * b; r.z = -2.0f * c;
    r.w = fmaf(a, a, fmaf(b, b, c * c));
    return r;
}
__device__ __forceinline__ float4 stage_y(const float* p) {
    float a = p[0], b = p[1], c = p[2];
    float4 r; r.x = a; r.y = b; r.z = c;
    r.w = fmaf(a, a, fmaf(b, b, c * c));
    return r;
}

// ================= MERGED PATH (needs ~12.6MB ws) =================
// Block-local shifts; per (row, col-block) partials (s,num,den); non-atomic.
// finalize2 rebases with exp2(s_g - s_b) <= 1 and combines.

__global__ __launch_bounds__(256)
void merged_pass(const float* __restrict__ x, const float* __restrict__ y,
                 float* __restrict__ sR, float* __restrict__ numR, float* __restrict__ denR,
                 float* __restrict__ sC, float* __restrict__ numC, float* __restrict__ denC) {
    const int bid = blockIdx.x;
    const int b   = bid / (NTI * NTJ);
    const int rem = bid % (NTI * NTJ);
    const int ib  = rem / NTJ, jb = rem % NTJ;
    const int i0  = ib * TI, j0 = jb * TJ;

    __shared__ float4 xs4[TI];
    __shared__ float4 ys4[TJ];
    __shared__ float  ar[TI], ac[TJ], rowmin_s[TI];
    __shared__ float  cm_w[4][TJ];
    __shared__ float  sn_w[4][TJ], sd_w[4][TJ];

    const int t = threadIdx.x;
    if (t < TI) xs4[t] = stage_x(&x[(size_t)(b * NN + i0 + t) * 3]);
    else        ys4[t - TI] = stage_y(&y[(size_t)(b * MM + j0 + (t - TI)) * 3]);
    __syncthreads();

    const int tx = t & 15, ty = t >> 4;
    const int lane = t & 63, wv = t >> 6;
    const int a16 = (lane ^ 16) << 2, a32 = (lane ^ 32) << 2;

    // packed Y fragments: pair p holds cols (2p, 2p+1)
    f32x2 Yx2[4], Yy2[4], Yz2[4], Yw2[4], cm2[4];
#pragma unroll
    for (int p = 0; p < 4; ++p) {
        float4 a = ys4[tx + (2 * p) * 16];
        float4 c = ys4[tx + (2 * p + 1) * 16];
        Yx2[p] = (f32x2){a.x, c.x}; Yy2[p] = (f32x2){a.y, c.y};
        Yz2[p] = (f32x2){a.z, c.z}; Yw2[p] = (f32x2){a.w, c.w};
        cm2[p] = (f32x2){1e30f, 1e30f};
    }

    // ---- micro-pass A: block-local row/col mins (packed) ----
#pragma unroll
    for (int k = 0; k < 8; ++k) {
        float4 Xv = xs4[ty + k * 16];
        f32x2 Xx2 = (f32x2){Xv.x, Xv.x}, Xy2 = (f32x2){Xv.y, Xv.y};
        f32x2 Xz2 = (f32x2){Xv.z, Xv.z}, Xw2 = (f32x2){Xv.w, Xv.w};
        f32x2 rm2 = (f32x2){1e30f, 1e30f};
#pragma unroll
        for (int p = 0; p < 4; ++p) {
            f32x2 pq = pair_d2_pk(Xx2, Xy2, Xz2, Xw2, Yx2[p], Yy2[p], Yz2[p], Yw2[p]);
            rm2 = vmin2(rm2, pq);
            cm2[p] = vmin2(cm2[p], pq);
        }
        float rmin = dpp_min16(fminf(rm2.x, rm2.y));
        if (tx == 15) rowmin_s[ty + k * 16] = rmin;   // row owned by one wave
    }
#pragma unroll
    for (int p = 0; p < 4; ++p) {
#pragma unroll
        for (int h = 0; h < 2; ++h) {
            float v = h ? cm2[p].y : cm2[p].x;
            v = fminf(v, bperm(v, a16));
            v = fminf(v, bperm(v, a32));
            if (lane < 16) cm_w[wv][lane + (2 * p + h) * 16] = v;
        }
    }
    __syncthreads();

    // ---- local shifts + write s partials ----
    if (t < TI) {
        float s = L2E100 * __builtin_amdgcn_sqrtf(fmaxf(rowmin_s[t], 0.0f));
        ar[t] = s;
        sR[(size_t)jb * NROW + b * NN + i0 + t] = s;
    } else {
        int j = t - TI;
        float m = fminf(fminf(cm_w[0][j], cm_w[1][j]), fminf(cm_w[2][j], cm_w[3][j]));
        float s = L2E100 * __builtin_amdgcn_sqrtf(fmaxf(m, 0.0f));
        ac[j] = s;
        sC[(size_t)ib * NCOL + b * MM + j0 + j] = s;
    }
    __syncthreads();

    // ---- micro-pass B: packed weighted sums with local shifts ----
    const f32x2 nL2 = (f32x2){-L2E100, -L2E100};
    f32x2 sc2[4], nc2[4], dc2[4];
#pragma unroll
    for (int p = 0; p < 4; ++p) {
        sc2[p] = (f32x2){ac[tx + (2 * p) * 16], ac[tx + (2 * p + 1) * 16]};
        nc2[p] = (f32x2){0.0f, 0.0f}; dc2[p] = (f32x2){0.0f, 0.0f};
    }

#pragma unroll
    for (int k = 0; k < 8; ++k) {
        float4 Xv = xs4[ty + k * 16];
        f32x2 Xx2 = (f32x2){Xv.x, Xv.x}, Xy2 = (f32x2){Xv.y, Xv.y};
        f32x2 Xz2 = (f32x2){Xv.z, Xv.z}, Xw2 = (f32x2){Xv.w, Xv.w};
        float srk = ar[ty + k * 16];
        f32x2 sr2 = (f32x2){srk, srk};
        f32x2 nr2 = (f32x2){0.0f, 0.0f}, dr2 = (f32x2){0.0f, 0.0f};
#pragma unroll
        for (int p = 0; p < 4; ++p) {
            f32x2 pq = pair_d2_pk(Xx2, Xy2, Xz2, Xw2, Yx2[p], Yy2[p], Yz2[p], Yw2[p]);
            f32x2 d  = vsqrt2(vmax0(pq));
            f32x2 eR = vexp2(d * nL2 + sr2);     // arg <= 0
            nr2 = d * eR + nr2;
            dr2 = dr2 + eR;
            f32x2 eC = vexp2(d * nL2 + sc2[p]);  // arg <= 0
            nc2[p] = d * eC + nc2[p];
            dc2[p] = dc2[p] + eC;
        }
        float vn = dpp_sum16(nr2.x + nr2.y);
        float vd = dpp_sum16(dr2.x + dr2.y);
        if (tx == 15) {
            size_t idx = (size_t)jb * NROW + b * NN + i0 + ty + k * 16;
            numR[idx] = vn;            // one writer per (row, jb)
            denR[idx] = vd;
        }
    }

#pragma unroll
    for (int p = 0; p < 4; ++p) {
#pragma unroll
        for (int h = 0; h < 2; ++h) {
            float vn = h ? nc2[p].y : nc2[p].x;
            float vd = h ? dc2[p].y : dc2[p].x;
            vn += bperm(vn, a16); vd += bperm(vd, a16);
            vn += bperm(vn, a32); vd += bperm(vd, a32);
            if (lane < 16) {
                sn_w[wv][lane + (2 * p + h) * 16] = vn;
                sd_w[wv][lane + (2 * p + h) * 16] = vd;
            }
        }
    }
    __syncthreads();
    if (t < TJ) {
        size_t idx = (size_t)ib * NCOL + b * MM + j0 + t;
        numC[idx] = (sn_w[0][t] + sn_w[1][t]) + (sn_w[2][t] + sn_w[3][t]);
        denC[idx] = (sd_w[0][t] + sd_w[1][t]) + (sd_w[2][t] + sd_w[3][t]);
    }
}

__global__ __launch_bounds__(256)
void finalize2(const float* __restrict__ sR, const float* __restrict__ numR, const float* __restrict__ denR,
               const float* __restrict__ sC, const float* __restrict__ numC, const float* __restrict__ denC,
               float* __restrict__ bsum) {
    const int gid = blockIdx.x * 256 + threadIdx.x;   // 0..32767
    const float* S; const float* NU; const float* DE; int idx;
    if (gid < NROW) { S = sR; NU = numR; DE = denR; idx = gid; }
    else            { S = sC; NU = numC; DE = denC; idx = gid - NROW; }

    float m = 1e30f;
#pragma unroll 4
    for (int pb = 0; pb < 32; ++pb) m = fminf(m, S[(size_t)pb * NROW + idx]);
    float nu = 0.0f, de = 0.0f;
#pragma unroll 4
    for (int pb = 0; pb < 32; ++pb) {
        size_t o = (size_t)pb * NROW + idx;
        float f = __builtin_amdgcn_exp2f(m - S[o]);   // <= 0 arg
        nu = fmaf(NU[o], f, nu);
        de = fmaf(DE[o], f, de);
    }
    float q = nu * __builtin_amdgcn_rcpf(de);         // de >= 1

#pragma unroll
    for (int s = 1; s < 64; s <<= 1) q += __shfl_xor(q, s);
    __shared__ float wsum[4];
    const int t = threadIdx.x;
    if ((t & 63) == 0) wsum[t >> 6] = q;
    __syncthreads();
    if (t == 0) bsum[blockIdx.x] = (wsum[0] + wsum[1]) + (wsum[2] + wsum[3]);
}

__global__ __launch_bounds__(256)
void final_sum(const float* __restrict__ bsum, float* __restrict__ out) {
    const int t = threadIdx.x;
    float s = (t < 128) ? bsum[t] : 0.0f;
#pragma unroll
    for (int m = 1; m < 64; m <<= 1) s += __shfl_xor(s, m);
    __shared__ float wsum[4];
    if ((t & 63) == 0) wsum[t >> 6] = s;
    __syncthreads();
    if (t == 0) out[0] = (wsum[0] + wsum[1] + wsum[2] + wsum[3]) * (1.0f / (float)(BB * NN));
}

// ================= FALLBACK PATH (384KB ws) =================
__global__ __launch_bounds__(256)
void init_ws_kernel(float* ws, float* out) {
    int idx = blockIdx.x * 256 + threadIdx.x;
    if (idx < 2 * 16384) ws[idx] = 1e30f;
    else if (idx < 6 * 16384) ws[idx] = 0.0f;
    if (idx == 0) out[0] = 0.0f;
}

__global__ __launch_bounds__(256)
void pass1_min(const float* __restrict__ x, const float* __restrict__ y,
               unsigned int* __restrict__ m2_row, unsigned int* __restrict__ m2_col) {
    const int bid = blockIdx.x;
    const int b   = bid / (NTI * NTJ);
    const int rem = bid % (NTI * NTJ);
    const int i0  = (rem / NTJ) * TI;
    const int j0  = (rem % NTJ) * TJ;

    __shared__ float4 xs4[TI];
    __shared__ float4 ys4[TJ];
    __shared__ float  cm_w[4][TJ];

    const int t = threadIdx.x;
    if (t < TI) xs4[t] = stage_x(&x[(size_t)(b * NN + i0 + t) * 3]);
    else        ys4[t - TI] = stage_y(&y[(size_t)(b * MM + j0 + (t - TI)) * 3]);
    __syncthreads();

    const int tx = t & 15, ty = t >> 4;
    const int lane = t & 63, wv = t >> 6;
    const int a16 = (lane ^ 16) << 2, a32 = (lane ^ 32) << 2;

    f32x2 Yx2[4], Yy2[4], Yz2[4], Yw2[4], cm2[4];
#pragma unroll
    for (int p = 0; p < 4; ++p) {
        float4 a = ys4[tx + (2 * p) * 16];
        float4 c = ys4[tx + (2 * p + 1) * 16];
        Yx2[p] = (f32x2){a.x, c.x}; Yy2[p] = (f32x2){a.y, c.y};
        Yz2[p] = (f32x2){a.z, c.z}; Yw2[p] = (f32x2){a.w, c.w};
        cm2[p] = (f32x2){1e30f, 1e30f};
    }
#pragma unroll
    for (int k = 0; k < 8; ++k) {
        float4 Xv = xs4[ty + k * 16];
        f32x2 Xx2 = (f32x2){Xv.x, Xv.x}, Xy2 = (f32x2){Xv.y, Xv.y};
        f32x2 Xz2 = (f32x2){Xv.z, Xv.z}, Xw2 = (f32x2){Xv.w, Xv.w};
        f32x2 rm2 = (f32x2){1e30f, 1e30f};
#pragma unroll
        for (int p = 0; p < 4; ++p) {
            f32x2 pq = pair_d2_pk(Xx2, Xy2, Xz2, Xw2, Yx2[p], Yy2[p], Yz2[p], Yw2[p]);
            rm2 = vmin2(rm2, pq);
            cm2[p] = vmin2(cm2[p], pq);
        }
        float rmin = dpp_min16(fminf(rm2.x, rm2.y));
        if (tx == 15) atomicMin(&m2_row[b * NN + i0 + ty + k * 16], __float_as_uint(rmin));
    }
#pragma unroll
    for (int p = 0; p < 4; ++p) {
#pragma unroll
        for (int h = 0; h < 2; ++h) {
            float v = h ? cm2[p].y : cm2[p].x;
            v = fminf(v, bperm(v, a16));
            v = fminf(v, bperm(v, a32));
            if (lane < 16) cm_w[wv][lane + (2 * p + h) * 16] = v;
        }
    }
    __syncthreads();
    if (t < TJ) {
        float m = fminf(fminf(cm_w[0][t], cm_w[1][t]), fminf(cm_w[2][t], cm_w[3][t]));
        atomicMin(&m2_col[b * MM + j0 + t], __float_as_uint(m));
    }
}

__global__ __launch_bounds__(256)
void pass2_acc(const float* __restrict__ x, const float* __restrict__ y,
               const unsigned int* __restrict__ m2_row, const unsigned int* __restrict__ m2_col,
               float* __restrict__ num_r, float* __restrict__ den_r,
               float* __restrict__ num_c, float* __restrict__ den_c) {
    const int bid = blockIdx.x;
    const int b   = bid / (NTI * NTJ);
    const int rem = bid % (NTI * NTJ);
    const int i0  = (rem / NTJ) * TI;
    const int j0  = (rem % NTJ) * TJ;

    __shared__ float4 xs4[TI];
    __shared__ float4 ys4[TJ];
    __shared__ float  ar[TI];
    __shared__ float  ac[TJ];
    __shared__ float  sn_w[4][TJ];
    __shared__ float  sd_w[4][TJ];

    const int t = threadIdx.x;
    if (t < TI) {
        xs4[t] = stage_x(&x[(size_t)(b * NN + i0 + t) * 3]);
        ar[t]  = L2E100 * __builtin_amdgcn_sqrtf(fmaxf(__uint_as_float(m2_row[b * NN + i0 + t]), 0.0f));
    } else {
        int j = t - TI;
        ys4[j] = stage_y(&y[(size_t)(b * MM + j0 + j) * 3]);
        ac[j]  = L2E100 * __builtin_amdgcn_sqrtf(fmaxf(__uint_as_float(m2_col[b * MM + j0 + j]), 0.0f));
    }
    __syncthreads();

    const int tx = t & 15, ty = t >> 4;
    const int lane = t & 63, wv = t >> 6;
    const int a16 = (lane ^ 16) << 2, a32 = (lane ^ 32) << 2;
    const f32x2 nL2 = (f32x2){-L2E100, -L2E100};

    f32x2 Yx2[4], Yy2[4], Yz2[4], Yw2[4], sc2[4], nc2[4], dc2[4];
#pragma unroll
    for (int p = 0; p < 4; ++p) {
        float4 a = ys4[tx + (2 * p) * 16];
        float4 c = ys4[tx + (2 * p + 1) * 16];
        Yx2[p] = (f32x2){a.x, c.x}; Yy2[p] = (f32x2){a.y, c.y};
        Yz2[p] = (f32x2){a.z, c.z}; Yw2[p] = (f32x2){a.w, c.w};
        sc2[p] = (f32x2){ac[tx + (2 * p) * 16], ac[tx + (2 * p + 1) * 16]};
        nc2[p] = (f32x2){0.0f, 0.0f}; dc2[p] = (f32x2){0.0f, 0.0f};
    }
#pragma unroll
    for (int k = 0; k < 8; ++k) {
        float4 Xv = xs4[ty + k * 16];
        f32x2 Xx2 = (f32x2){Xv.x, Xv.x}, Xy2 = (f32x2){Xv.y, Xv.y};
        f32x2 Xz2 = (f32x2){Xv.z, Xv.z}, Xw2 = (f32x2){Xv.w, Xv.w};
        float srk = ar[ty + k * 16];
        f32x2 sr2 = (f32x2){srk, srk};
        f32x2 nr2 = (f32x2){0.0f, 0.0f}, dr2 = (f32x2){0.0f, 0.0f};
#pragma unroll
        for (int p = 0; p < 4; ++p) {
            f32x2 pq = pair_d2_pk(Xx2, Xy2, Xz2, Xw2, Yx2[p], Yy2[p], Yz2[p], Yw2[p]);
            f32x2 d  = vsqrt2(vmax0(pq));
            f32x2 eR = vexp2(d * nL2 + sr2);
            nr2 = d * eR + nr2;
            dr2 = dr2 + eR;
            f32x2 eC = vexp2(d * nL2 + sc2[p]);
            nc2[p] = d * eC + nc2[p];
            dc2[p] = dc2[p] + eC;
        }
        float vn = dpp_sum16(nr2.x + nr2.y);
        float vd = dpp_sum16(dr2.x + dr2.y);
        if (tx == 15) {
            atomicAdd(&num_r[b * NN + i0 + ty + k * 16], vn);
            atomicAdd(&den_r[b * NN + i0 + ty + k * 16], vd);
        }
    }
#pragma unroll
    for (int p = 0; p < 4; ++p) {
#pragma unroll
        for (int h = 0; h < 2; ++h) {
            float vn = h ? nc2[p].y : nc2[p].x;
            float vd = h ? dc2[p].y : dc2[p].x;
            vn += bperm(vn, a16); vd += bperm(vd, a16);
            vn += bperm(vn, a32); vd += bperm(vd, a32);
            if (lane < 16) {
                sn_w[wv][lane + (2 * p + h) * 16] = vn;
                sd_w[wv][lane + (2 * p + h) * 16] = vd;
            }
        }
    }
    __syncthreads();
    if (t < TJ) {
        atomicAdd(&num_c[b * MM + j0 + t], (sn_w[0][t] + sn_w[1][t]) + (sn_w[2][t] + sn_w[3][t]));
        atomicAdd(&den_c[b * MM + j0 + t], (sd_w[0][t] + sd_w[1][t]) + (sd_w[2][t] + sd_w[3][t]));
    }
}

__global__ __launch_bounds__(256)
void finalize_kernel(const float* __restrict__ num_r, const float* __restrict__ den_r,
                     const float* __restrict__ num_c, const float* __restrict__ den_c,
                     float* __restrict__ out) {
    const int gid = blockIdx.x * 256 + threadIdx.x;
    float s = 0.0f;
    for (int idx = gid; idx < BB * NN; idx += 32 * 256) {
        s = fmaf(num_r[idx], __builtin_amdgcn_rcpf(den_r[idx]), s);
        s = fmaf(num_c[idx], __builtin_amdgcn_rcpf(den_c[idx]), s);
    }
#pragma unroll
    for (int m = 1; m < 64; m <<= 1) s += __shfl_xor(s, m);
    __shared__ float wsum[4];
    const int t = threadIdx.x;
    if ((t & 63) == 0) wsum[t >> 6] = s;
    __syncthreads();
    if (t == 0) {
        float v = (wsum[0] + wsum[1] + wsum[2] + wsum[3]) * (1.0f / (float)(BB * NN));
        atomicAdd(out, v);
    }
}

extern "C" void kernel_launch(void* const* d_in, const int* in_sizes, int n_in,
                              void* d_out, int out_size, void* d_ws, size_t ws_size,
                              hipStream_t stream) {
    const float* x = (const float*)d_in[0];
    const float* y = (const float*)d_in[1];
    float* ws = (float*)d_ws;

    const size_t PART = (size_t)32 * NROW;      // 524288 floats per partial array
    const size_t need = (6 * PART + 256) * sizeof(float);  // ~12.6MB

    if (ws_size >= need) {
        float* sR   = ws;
        float* numR = ws + PART;
        float* denR = ws + 2 * PART;
        float* sC   = ws + 3 * PART;
        float* numC = ws + 4 * PART;
        float* denC = ws + 5 * PART;
        float* bsum = ws + 6 * PART;

        hipLaunchKernelGGL(merged_pass, dim3(BB * NTI * NTJ), dim3(256), 0, stream,
                           x, y, sR, numR, denR, sC, numC, denC);
        hipLaunchKernelGGL(finalize2, dim3(128), dim3(256), 0, stream,
                           sR, numR, denR, sC, numC, denC, bsum);
        hipLaunchKernelGGL(final_sum, dim3(1), dim3(256), 0, stream, bsum, (float*)d_out);
    } else {
        unsigned int* m2_row = (unsigned int*)(ws);
        unsigned int* m2_col = (unsigned int*)(ws + 16384);
        float* num_r = ws + 32768;
        float* den_r = ws + 49152;
        float* num_c = ws + 65536;
        float* den_c = ws + 81920;

        hipLaunchKernelGGL(init_ws_kernel, dim3(384), dim3(256), 0, stream, ws, (float*)d_out);
        dim3 grid(BB * NTI * NTJ);
        hipLaunchKernelGGL(pass1_min, grid, dim3(256), 0, stream, x, y, m2_row, m2_col);
        hipLaunchKernelGGL(pass2_acc, grid, dim3(256), 0, stream,
                           x, y, m2_row, m2_col, num_r, den_r, num_c, den_c);
        hipLaunchKernelGGL(finalize_kernel, dim3(32), dim3(256), 0, stream,
                           num_r, den_r, num_c, den_c, (float*)d_out);
    }
}